// Round 8
// baseline (281.301 us; speedup 1.0000x reference)
//
#include <hip/hip_runtime.h>
#include <hip/hip_bf16.h>

// Problem constants (match reference setup_inputs / hyperparams)
constexpr int B  = 4;
constexpr int H  = 544;
constexpr int W  = 960;
constexpr int H2 = 272;   // half-res
constexpr int W2 = 480;
constexpr int NH = B * H2 * W2;     // 522240
constexpr int NF = B * H * W;       // 2088960

// pixel kernel tiling (R16): 64x16 outputs per block @1024 threads, halo 1 -> 66x18
constexpr int TPW = 64, TPH = 16;
constexpr int SW = TPW + 2, SH = TPH + 2;      // 66 x 18
constexpr int NSTAGE = SW * SH;                // 1188
constexpr int GX = W / TPW;                    // 15
constexpr int GY = H / TPH;                    // 34
constexpr int NBLK  = GX * GY * B;             // 2040 (k_pix blocks)
constexpr int NBLK3 = 8 * 34 * B;              // 1088 merged k_ncc blocks

__device__ inline float waveSum(float v) {
  #pragma unroll
  for (int off = 32; off > 0; off >>= 1) v += __shfl_down(v, off, 64);
  return v;
}

// ------- fused pixel kernel: gt + photometric + smoothness + lg/rg downsample -------
// R16: 64x16 tile @1024 threads. R17 adds: block 0 zeroes the k_ncc completion
// ticket (safe: stream order puts all of k_pix before any k_ncc block).
__global__ __launch_bounds__(1024) void k_pix(const float* __restrict__ pred,
                                              const float* __restrict__ gt,
                                              const float* __restrict__ conf,
                                              const float* __restrict__ occ,
                                              const float* __restrict__ left,
                                              const float* __restrict__ right,
                                              float* __restrict__ lg,
                                              float* __restrict__ rg,
                                              float* __restrict__ partialsA,
                                              unsigned int* __restrict__ counter) {
  const int bx = blockIdx.x % GX;
  const int by = (blockIdx.x / GX) % GY;
  const int b  = blockIdx.x / (GX * GY);
  const int x0 = bx * TPW, y0 = by * TPH;
  const int tid = threadIdx.x;

  if (blockIdx.x == 0 && tid == 0) atomicExch(counter, 0u);

  const float* dispb = pred + (size_t)b * H * W;
  const float* lb = left  + (size_t)b * 3 * H * W;
  const float* rb = right + (size_t)b * 3 * H * W;

  __shared__ float4 L4s[NSTAGE];   // (lv0, lv1, lv2, disp); zeros if OOB
  __shared__ float4 W4s[NSTAGE];   // (wv0, wv1, wv2, 0);    zeros if OOB

  for (int e = tid; e < NSTAGE; e += 1024) {
    int r = e / SW, c = e % SW;
    int yy = y0 - 1 + r, xx = x0 - 1 + c;
    float4 l4 = make_float4(0.f, 0.f, 0.f, 0.f);
    float4 w4 = make_float4(0.f, 0.f, 0.f, 0.f);
    if (yy >= 0 && yy < H && xx >= 0 && xx < W) {
      float dv = dispb[yy * W + xx];
      float xsv = (float)xx - dv;
      float xc = fminf(fmaxf(xsv, 0.f), (float)(W - 1));
      float x0f = floorf(xc);
      float w = xc - x0f;
      int x0i = (int)x0f;
      int x1i = min(x0i + 1, W - 1);
      const float* l0 = lb + (size_t)yy * W;
      const float* r0 = rb + (size_t)yy * W;
      l4.x = l0[xx];
      l4.y = l0[(size_t)H * W + xx];
      l4.z = l0[2 * (size_t)H * W + xx];
      l4.w = dv;
      w4.x = r0[x0i] * (1.f - w) + r0[x1i] * w;
      w4.y = r0[(size_t)H * W + x0i] * (1.f - w) + r0[(size_t)H * W + x1i] * w;
      w4.z = r0[2 * (size_t)H * W + x0i] * (1.f - w) + r0[2 * (size_t)H * W + x1i] * w;
    }
    L4s[e] = l4; W4s[e] = w4;
  }
  __syncthreads();

  // ---- lg/rg emission (threads 0..255): 32x8 half-res pixels of this tile ----
  if (tid < 256) {
    int hx = tid & 31, hy = tid >> 5;
    int y2g = (y0 >> 1) + hy, x2g = (x0 >> 1) + hx;
    int i00 = (2 * hy + 1) * SW + (2 * hx + 1);
    float4 a00 = L4s[i00], a01 = L4s[i00 + 1], a10 = L4s[i00 + SW], a11 = L4s[i00 + SW + 1];
    float sl = 0.f;
    sl += a00.x + a01.x + a10.x + a11.x;
    sl += a00.y + a01.y + a10.y + a11.y;
    sl += a00.z + a01.z + a10.z + a11.z;
    float sr = 0.f;
    int yy2 = y0 + 2 * hy, xx2 = x0 + 2 * hx;
    #pragma unroll
    for (int c = 0; c < 3; c++) {
      const float* rp = rb + (size_t)(c * H + yy2) * W + xx2;
      sr += rp[0] + rp[1] + rp[W] + rp[W + 1];
    }
    size_t ho = (size_t)b * (H2 * W2) + (size_t)y2g * W2 + x2g;
    lg[ho] = sl * (1.f / 12.f);
    rg[ho] = sr * (1.f / 12.f);
  }

  float v[6];
  #pragma unroll
  for (int s = 0; s < 6; s++) v[s] = 0.f;

  {
    const int tx = tid & 63, ty = tid >> 6;
    const int x = x0 + tx, y = y0 + ty;
    const size_t gidx = (size_t)b * H * W + (size_t)y * W + x;
    const int ci = (ty + 1) * SW + (tx + 1);

    float sl[3] = {0,0,0}, sw[3] = {0,0,0}, sl2[3] = {0,0,0},
          sw2[3] = {0,0,0}, slw[3] = {0,0,0};
    float4 cl4, cw4, rl4, dl4;
    #pragma unroll
    for (int dy = -1; dy <= 1; dy++) {
      #pragma unroll
      for (int dx = -1; dx <= 1; dx++) {
        int ni = ci + dy * SW + dx;
        float4 a = L4s[ni];
        float4 wv = W4s[ni];
        sl[0] += a.x;  sl2[0] += a.x * a.x;  sw[0] += wv.x;  sw2[0] += wv.x * wv.x;  slw[0] += a.x * wv.x;
        sl[1] += a.y;  sl2[1] += a.y * a.y;  sw[1] += wv.y;  sw2[1] += wv.y * wv.y;  slw[1] += a.y * wv.y;
        sl[2] += a.z;  sl2[2] += a.z * a.z;  sw[2] += wv.z;  sw2[2] += wv.z * wv.z;  slw[2] += a.z * wv.z;
        if (dy == 0 && dx == 0) { cl4 = a; cw4 = wv; }
        if (dy == 0 && dx == 1) rl4 = a;
        if (dy == 1 && dx == 0) dl4 = a;
      }
    }
    float ds = cl4.w;

    // ---- gt anchor ----
    {
      float g = gt[gidx];
      float trust = (g > 2.0f) ? conf[gidx] * occ[gidx] : 0.f;
      v[0] = trust * fabsf(ds - g);
      v[1] = trust;
    }

    // ---- photometric ----
    {
      float xs = (float)x - ds;
      bool valid = (xs > 0.f) && (xs < (float)(W - 1));
      float cl[3] = {cl4.x, cl4.y, cl4.z};
      float cw[3] = {cw4.x, cw4.y, cw4.z};
      float ssm = 0.f, l1m = 0.f;
      #pragma unroll
      for (int c = 0; c < 3; c++) {
        float mx = sl[c] * (1.f / 9.f), my = sw[c] * (1.f / 9.f);
        float sx = fmaxf(sl2[c] * (1.f / 9.f) - mx * mx, 0.f);
        float sy = fmaxf(sw2[c] * (1.f / 9.f) - my * my, 0.f);
        float sxy = slw[c] * (1.f / 9.f) - mx * my;
        float n  = (2.f * mx * my + 1e-4f) * (2.f * sxy + 9e-4f);
        float dd = (mx * mx + my * my + 1e-4f) * (sx + sy + 9e-4f);
        float ss = (1.f - n / dd) * 0.5f;
        ss = fminf(fmaxf(ss, 0.f), 1.f);
        ssm += ss;
        l1m += fabsf(cl[c] - cw[c]);
      }
      ssm *= (1.f / 3.f); l1m *= (1.f / 3.f);
      float err = 0.85f * ssm + 0.15f * l1m;
      if (valid) { v[2] = err; v[3] = 1.f; }
    }

    // ---- smoothness ----
    if (x < W - 1) {
      float ddx = fabsf(rl4.w - ds);
      float idx = fabsf(rl4.x - cl4.x) + fabsf(rl4.y - cl4.y) + fabsf(rl4.z - cl4.z);
      v[4] = ddx * __expf(-idx * (1.f / 3.f));
    }
    if (y < H - 1) {
      float ddy = fabsf(dl4.w - ds);
      float idy = fabsf(dl4.x - cl4.x) + fabsf(dl4.y - cl4.y) + fabsf(dl4.z - cl4.z);
      v[5] = ddy * __expf(-idy * (1.f / 3.f));
    }
  }

  __shared__ float sm[16][6];
  int wave = threadIdx.x >> 6, lane = threadIdx.x & 63;
  #pragma unroll
  for (int s = 0; s < 6; s++) {
    float r = waveSum(v[s]);
    if (lane == 0) sm[wave][s] = r;
  }
  __syncthreads();
  if (threadIdx.x < 6) {
    float t = 0.f;
    #pragma unroll
    for (int q = 0; q < 16; q++) t += sm[q][threadIdx.x];
    partialsA[(size_t)threadIdx.x * NBLK + blockIdx.x] = t;
  }
}

// -------- fused NCC disparity search, ALL 48 d's + inline sign/mag (R17) ----------
// R17 = R16 (verified) + last-block final reduction (threadFenceReduction
// pattern): after writing partialsB every block fences + takes a ticket; the
// last block reduces partialsA/partialsB (L2-warm) and writes out[0].
// Eliminates the k_final launch + gap + its cold single-block reads.
// LDS layout identical to R16 (26768 B + flag; alloc unchanged at 27136):
//   @0:    LGs 18x74=1332 (dead after LH) overlaid by RM 8x112 @0, RS @896
//   @1792: RGs 18x122 = 2196 | @3988: POOL 2304 | @6292: P1 8x25 | @6492: P2
__global__ __launch_bounds__(256) void k_ncc(const float* __restrict__ lg,
                                             const float* __restrict__ rg,
                                             const float* __restrict__ pred,
                                             const float* __restrict__ PA,
                                             float* __restrict__ partialsB,
                                             unsigned int* __restrict__ counter,
                                             float* __restrict__ out) {
  const int b = blockIdx.z;
  const int x0 = blockIdx.x * 64;
  const int y0 = blockIdx.y * 8;
  const int tid = threadIdx.x;

  __shared__ __align__(16) float SM[6692];
  __shared__ unsigned int lastFlag;
  float* LGs = SM;             // 18 x 74
  float* RM  = SM;             // 8 x 112 (overlays dead LGs)
  float* RS  = SM + 896;       // 8 x 112
  float* RGs = SM + 1792;      // 18 x 122
  float* POOL = SM + 3988;     // 2304
  float* P1 = SM + 6292;       // 8 x 25
  float* P2 = SM + 6492;

  const float* lgb = lg + (size_t)b * (H2 * W2);
  const float* rgb = rg + (size_t)b * (H2 * W2);

  for (int e = tid; e < 18 * 74; e += 256) {
    int r = e / 74, c = e % 74;
    int gy = y0 - 5 + r, gxx = x0 - 5 + c;
    LGs[e] = (gy >= 0 && gy < H2 && gxx >= 0 && gxx < W2) ? lgb[gy * W2 + gxx] : 0.f;
  }
  const int col0RG = x0 - 29;       // x0 - 5 + dmin, dmin = -24
  for (int e = tid; e < 18 * 122; e += 256) {
    int r = e / 122, c = e % 122;
    int gy = y0 - 5 + r, gxx = col0RG + c;
    RGs[e] = (gy >= 0 && gy < H2 && gxx >= 0 && gxx < W2) ? rgb[gy * W2 + gxx] : 0.f;
  }
  __syncthreads();

  // ---- LH pass (horizontal 11-sums of lg, lg^2) + lgc register cache ----
  const int hg = tid & 7, hr = tid >> 3;
  float lgc[18];
  float* LH1 = POOL;           // 18 x 64
  float* LH2 = POOL + 1152;
  if (hr < 18) {
    #pragma unroll
    for (int k = 0; k < 18; k++) lgc[k] = LGs[hr * 74 + 8 * hg + k];
    float w1[8], w2[8];
    float s1 = 0.f, s2 = 0.f;
    #pragma unroll
    for (int k = 0; k < 11; k++) { s1 += lgc[k]; s2 += lgc[k] * lgc[k]; }
    w1[0] = s1; w2[0] = s2;
    #pragma unroll
    for (int j = 1; j < 8; j++) {
      s1 += lgc[j + 10] - lgc[j - 1];
      s2 += lgc[j + 10] * lgc[j + 10] - lgc[j - 1] * lgc[j - 1];
      w1[j] = s1; w2[j] = s2;
    }
    *(float4*)&LH1[hr * 64 + 8 * hg]     = make_float4(w1[0], w1[1], w1[2], w1[3]);
    *(float4*)&LH1[hr * 64 + 8 * hg + 4] = make_float4(w1[4], w1[5], w1[6], w1[7]);
    *(float4*)&LH2[hr * 64 + 8 * hg]     = make_float4(w2[0], w2[1], w2[2], w2[3]);
    *(float4*)&LH2[hr * 64 + 8 * hg + 4] = make_float4(w2[4], w2[5], w2[6], w2[7]);
  }
  // ---- border column sums (head: global cols 0..23; tail: 456..479) ----
  const bool headT = (x0 == 0);
  const bool tailT = (x0 == 448);
  if (headT || tailT) {
    int gcol0 = headT ? 0 : 456;
    for (int e = tid; e < 8 * 24; e += 256) {
      int y = e / 24, i = e % 24;
      int lc = gcol0 + i - col0RG;
      float v1 = 0.f, v2 = 0.f;
      if (lc >= 0 && lc < 122) {
        #pragma unroll
        for (int dy = 0; dy < 11; dy++) {
          float v = RGs[(y + dy) * 122 + lc];
          v1 += v; v2 += v * v;
        }
      }
      P1[y * 25 + i + 1] = v1;
      P2[y * 25 + i + 1] = v2;
    }
  }
  __syncthreads();

  if ((headT || tailT) && tid < 8) {
    int y = tid;
    float s1 = 0.f, s2 = 0.f;
    P1[y * 25] = 0.f; P2[y * 25] = 0.f;
    for (int k = 0; k < 24; k++) {
      s1 += P1[y * 25 + k + 1]; P1[y * 25 + k + 1] = s1;
      s2 += P2[y * 25 + k + 1]; P2[y * 25 + k + 1] = s2;
    }
  }
  const int vx = tid & 63;
  const int vys = (tid >> 6) * 2;    // 4 waves x 2 rows = 8 output rows
  float lmS[2], lsS[2];   // 121-scaled left mean / std
  {
    float s1 = 0.f, s2 = 0.f;
    #pragma unroll
    for (int dy = 0; dy < 11; dy++) { s1 += LH1[(vys + dy) * 64 + vx]; s2 += LH2[(vys + dy) * 64 + vx]; }
    #pragma unroll
    for (int k = 0; k < 2; k++) {
      if (k) {
        s1 += LH1[(vys + k + 10) * 64 + vx] - LH1[(vys + k - 1) * 64 + vx];
        s2 += LH2[(vys + k + 10) * 64 + vx] - LH2[(vys + k - 1) * 64 + vx];
      }
      float m = s1 * (1.f / 121.f);
      float s = sqrtf(fmaxf(s2 * (1.f / 121.f) - m * m, 1e-8f));
      lmS[k] = m * 121.f;
      lsS[k] = s * 121.f;
    }
  }
  __syncthreads();

  // ---- VR pass: vertical 11-sums of rg, rg^2 (POOL, overwrites LH) ----
  float* VR1 = POOL;           // 8 x 122
  float* VR2 = POOL + 976;
  if (tid < 244) {
    int c = tid % 122;
    int rr0 = (tid / 122) * 4;
    float s1 = 0.f, s2 = 0.f;
    #pragma unroll
    for (int dy = 0; dy < 11; dy++) {
      float v = RGs[(rr0 + dy) * 122 + c];
      s1 += v; s2 += v * v;
    }
    VR1[rr0 * 122 + c] = s1; VR2[rr0 * 122 + c] = s2;
    #pragma unroll
    for (int k = 1; k < 4; k++) {
      float vin  = RGs[(rr0 + k + 10) * 122 + c];
      float vout = RGs[(rr0 + k - 1) * 122 + c];
      s1 += vin - vout;
      s2 += vin * vin - vout * vout;
      VR1[(rr0 + k) * 122 + c] = s1; VR2[(rr0 + k) * 122 + c] = s2;
    }
  }
  __syncthreads();

  // ---- RV pass fused with moment transform -> planar RM (mean), RS (std) ----
  {
    int r = tid >> 5, seg = tid & 31;
    int c0 = seg * 4;
    if (c0 < 112) {
      float s1 = 0.f, s2 = 0.f;
      #pragma unroll
      for (int m = 0; m < 11; m++) { s1 += VR1[r * 122 + c0 + m]; s2 += VR2[r * 122 + c0 + m]; }
      #pragma unroll
      for (int j = 0; j < 4; j++) {
        if (j) {
          s1 += VR1[r * 122 + c0 + j + 10] - VR1[r * 122 + c0 + j - 1];
          s2 += VR2[r * 122 + c0 + j + 10] - VR2[r * 122 + c0 + j - 1];
        }
        float rm = s1 * (1.f / 121.f);
        float rstd = sqrtf(fmaxf(s2 * (1.f / 121.f) - rm * rm, 1e-8f));
        RM[r * 112 + c0 + j] = rm;
        RS[r * 112 + c0 + j] = rstd;
      }
    }
  }
  __syncthreads();

  // ---- d loop: 24 pairs covering d in [-24..-1] u [1..24], ascending ----
  float* CH0 = POOL;           // 18 x 64
  float* CH1 = POOL + 1152;
  const int gx = x0 + vx;
  float bnum[2], bden[2], bdd[2];
  #pragma unroll
  for (int k = 0; k < 2; k++) { bnum[k] = -1.f; bden[k] = 1.f; bdd[k] = 0.f; }

  for (int it = 0; it < 24; ++it) {
    const int d0 = (it < 12) ? (2 * it - 24) : (2 * it - 23);
    if (hr < 18) {
      const int c0 = 8 * hg + d0 + 24;
      float rgv[19];
      #pragma unroll
      for (int j = 0; j < 19; j++) rgv[j] = RGs[hr * 122 + c0 + j];
      float ca[8], cb[8];
      float sa = 0.f, sb = 0.f;
      #pragma unroll
      for (int k = 0; k < 11; k++) { sa += lgc[k] * rgv[k]; sb += lgc[k] * rgv[k + 1]; }
      ca[0] = sa; cb[0] = sb;
      #pragma unroll
      for (int j = 1; j < 8; j++) {
        sa += lgc[j + 10] * rgv[j + 10] - lgc[j - 1] * rgv[j - 1];
        sb += lgc[j + 10] * rgv[j + 11] - lgc[j - 1] * rgv[j];
        ca[j] = sa; cb[j] = sb;
      }
      *(float4*)&CH0[hr * 64 + 8 * hg]     = make_float4(ca[0], ca[1], ca[2], ca[3]);
      *(float4*)&CH0[hr * 64 + 8 * hg + 4] = make_float4(ca[4], ca[5], ca[6], ca[7]);
      *(float4*)&CH1[hr * 64 + 8 * hg]     = make_float4(cb[0], cb[1], cb[2], cb[3]);
      *(float4*)&CH1[hr * 64 + 8 * hg + 4] = make_float4(cb[4], cb[5], cb[6], cb[7]);
    }
    __syncthreads();
    {
      float a0 = 0.f, a1 = 0.f;
      #pragma unroll
      for (int dy = 0; dy < 11; dy++) { a0 += CH0[(vys + dy) * 64 + vx]; a1 += CH1[(vys + dy) * 64 + vx]; }
      #pragma unroll
      for (int k = 0; k < 2; k++) {
        if (k) {
          a0 += CH0[(vys + k + 10) * 64 + vx] - CH0[(vys + k - 1) * 64 + vx];
          a1 += CH1[(vys + k + 10) * 64 + vx] - CH1[(vys + k - 1) * 64 + vx];
        }
        #pragma unroll
        for (int h = 0; h < 2; h++) {
          int d = d0 + h;
          float cs = h ? a1 : a0;            // raw 121-sum of lg*rg_shift
          int rvi = vx + d + 24;
          float rm   = RM[(vys + k) * 112 + rvi];
          float rstd = RS[(vys + k) * 112 + rvi];
          bool eh = (d > 0) ? (gx < 5) : (gx > 474);   // implies x0==0 / x0==448
          if (eh) {
            float rs = rm * 121.f;
            float r2 = (rstd * rstd + rm * rm) * 121.f;
            int a, bI;
            if (d > 0) { a = max(gx - 5 + d, 0); bI = d; }
            else       { a = 24 + d; bI = min(gx + 5 + d, 479) - 455; }
            rs -= P1[(vys + k) * 25 + bI] - P1[(vys + k) * 25 + a];
            r2 -= P2[(vys + k) * 25 + bI] - P2[(vys + k) * 25 + a];
            rm = rs * (1.f / 121.f);
            rstd = sqrtf(fmaxf(r2 * (1.f / 121.f) - rm * rm, 1e-8f));
          }
          float num = __builtin_fmaf(-lmS[k], rm, cs);
          float den = __builtin_fmaf(lsS[k], rstd, 1.21e-6f);
          if (num * bden[k] > bnum[k] * den) { bnum[k] = num; bden[k] = den; bdd[k] = (float)d; }
        }
      }
    }
    __syncthreads();
  }

  // ---- inline sign/magnitude epilogue (was k_sgm) ----
  float v6 = 0.f, v7 = 0.f, v8 = 0.f;
  if (gx < W2) {
    const float* pb = pred + (size_t)b * H * W;
    #pragma unroll
    for (int k = 0; k < 2; k++) {
      float bc = bnum[k] / bden[k];
      if (bc > 0.3f) {
        float nd = bdd[k] * 2.f;
        float sgn = (nd > 0.f) ? 1.f : ((nd < 0.f) ? -1.f : 0.f);
        const float* p0 = pb + (size_t)(2 * (y0 + vys + k)) * W + 2 * gx;
        float p00 = p0[0], p01 = p0[1];
        float p10 = p0[W], p11 = p0[W + 1];
        v6 += fmaxf(-p00 * sgn, 0.f) + fmaxf(-p01 * sgn, 0.f)
            + fmaxf(-p10 * sgn, 0.f) + fmaxf(-p11 * sgn, 0.f);
        v7 += bc * (fabsf(p00 - nd) + fabsf(p01 - nd)
                  + fabsf(p10 - nd) + fabsf(p11 - nd));
        v8 += 4.f;
      }
    }
  }
  // block reduce into P1 region (P tables dead after d-loop)
  float* red = P1;   // 4 waves x 3 sums
  int wave = tid >> 6, lane = tid & 63;
  float r;
  r = waveSum(v6); if (lane == 0) red[wave * 3 + 0] = r;
  r = waveSum(v7); if (lane == 0) red[wave * 3 + 1] = r;
  r = waveSum(v8); if (lane == 0) red[wave * 3 + 2] = r;
  __syncthreads();
  if (tid < 3) {
    float t = red[0 * 3 + tid] + red[1 * 3 + tid] +
              red[2 * 3 + tid] + red[3 * 3 + tid];
    int bid = ((int)blockIdx.z * 34 + (int)blockIdx.y) * 8 + (int)blockIdx.x;
    partialsB[(size_t)tid * NBLK3 + bid] = t;
  }

  // ---- ticket: last block performs the final reduction (was k_final) ----
  __threadfence();                       // release partialsB (all threads)
  __syncthreads();
  if (tid == 0) {
    unsigned int old = atomicAdd(counter, 1u);
    lastFlag = (old == (unsigned int)(NBLK3 - 1)) ? 1u : 0u;
  }
  __syncthreads();
  if (lastFlag) {
    __threadfence();                     // acquire other blocks' partials
    float* red9 = P2;                    // 9 x 4 floats (P2 dead)
    #pragma unroll
    for (int s = 0; s < 6; s++) {
      float l = 0.f;
      for (int i = tid; i < NBLK; i += 256) l += PA[(size_t)s * NBLK + i];
      l = waveSum(l);
      if (lane == 0) red9[s * 4 + wave] = l;
    }
    #pragma unroll
    for (int s = 0; s < 3; s++) {
      float l = 0.f;
      for (int i = tid; i < NBLK3; i += 256) l += partialsB[(size_t)s * NBLK3 + i];
      l = waveSum(l);
      if (lane == 0) red9[(6 + s) * 4 + wave] = l;
    }
    __syncthreads();
    if (tid == 0) {
      float a[9];
      #pragma unroll
      for (int s = 0; s < 9; s++)
        a[s] = red9[s * 4 + 0] + red9[s * 4 + 1] + red9[s * 4 + 2] + red9[s * 4 + 3];
      float gtl = a[0] / fmaxf(a[1], 1.f);
      float ph  = a[2] / fmaxf(a[3], 1.f);
      float n   = fmaxf(a[8], 1.f);
      float smv = 0.3f * (a[6] / n) + 0.7f * (a[7] / n);
      float smo = a[4] * (1.f / ((float)B * H * (W - 1)))
                + a[5] * (1.f / ((float)B * (H - 1) * W));
      out[0] = gtl + ph + 0.5f * smv + 0.1f * smo;
    }
  }
}

extern "C" void kernel_launch(void* const* d_in, const int* in_sizes, int n_in,
                              void* d_out, int out_size, void* d_ws, size_t ws_size,
                              hipStream_t stream) {
  const float* pred  = (const float*)d_in[0];
  const float* gt    = (const float*)d_in[1];
  const float* conf  = (const float*)d_in[2];
  const float* occ   = (const float*)d_in[3];
  const float* left  = (const float*)d_in[4];
  const float* right = (const float*)d_in[5];
  float* out = (float*)d_out;

  float* ws = (float*)d_ws;
  float* lg  = ws;
  float* rg  = ws + (size_t)NH;
  float* partialsA = ws + 2 * (size_t)NH;            // 6 * NBLK
  float* partialsB = partialsA + 6 * (size_t)NBLK;   // 3 * NBLK3
  unsigned int* counter = (unsigned int*)(partialsB + 3 * (size_t)NBLK3);

  k_pix<<<NBLK, 1024, 0, stream>>>(pred, gt, conf, occ, left, right,
                                   lg, rg, partialsA, counter);

  dim3 nccGrid(8, 34, B);   // x-tiles, y-tiles (272/8), batch (all d's per block)
  k_ncc<<<nccGrid, 256, 0, stream>>>(lg, rg, pred, partialsA, partialsB,
                                     counter, out);
}

// Round 9
// 221.023 us; speedup vs baseline: 1.2727x; 1.2727x over previous
//
#include <hip/hip_runtime.h>
#include <hip/hip_bf16.h>

// Problem constants (match reference setup_inputs / hyperparams)
constexpr int B  = 4;
constexpr int H  = 544;
constexpr int W  = 960;
constexpr int H2 = 272;   // half-res
constexpr int W2 = 480;
constexpr int NH = B * H2 * W2;     // 522240
constexpr int NF = B * H * W;       // 2088960

// pixel kernel tiling: 64x16 outputs per block @1024 threads, halo 1 -> 66x18
constexpr int TPW = 64, TPH = 16;
constexpr int SW = TPW + 2, SH = TPH + 2;      // 66 x 18
constexpr int NSTAGE = SW * SH;                // 1188
constexpr int GX = W / TPW;                    // 15
constexpr int GY = H / TPH;                    // 34
constexpr int NBLK  = GX * GY * B;             // 2040 (k_pix blocks)
constexpr int NBLK3 = 8 * 34 * B;              // 1088 merged k_ncc blocks

__device__ inline float waveSum(float v) {
  #pragma unroll
  for (int off = 32; off > 0; off >>= 1) v += __shfl_down(v, off, 64);
  return v;
}

// ------- fused pixel kernel: gt + photometric + smoothness + lg/rg downsample -------
// R18: block sums go straight to double accumulators via relaxed atomicAdd
// (native f64 atomic at the coherence point — no fence, no partials array).
// Visibility to k_ncc's reader is guaranteed by the kernel-dispatch boundary.
__global__ __launch_bounds__(1024) void k_pix(const float* __restrict__ pred,
                                              const float* __restrict__ gt,
                                              const float* __restrict__ conf,
                                              const float* __restrict__ occ,
                                              const float* __restrict__ left,
                                              const float* __restrict__ right,
                                              float* __restrict__ lg,
                                              float* __restrict__ rg,
                                              double* __restrict__ acc) {
  const int bx = blockIdx.x % GX;
  const int by = (blockIdx.x / GX) % GY;
  const int b  = blockIdx.x / (GX * GY);
  const int x0 = bx * TPW, y0 = by * TPH;
  const int tid = threadIdx.x;

  const float* dispb = pred + (size_t)b * H * W;
  const float* lb = left  + (size_t)b * 3 * H * W;
  const float* rb = right + (size_t)b * 3 * H * W;

  __shared__ float4 L4s[NSTAGE];   // (lv0, lv1, lv2, disp); zeros if OOB
  __shared__ float4 W4s[NSTAGE];   // (wv0, wv1, wv2, 0);    zeros if OOB

  for (int e = tid; e < NSTAGE; e += 1024) {
    int r = e / SW, c = e % SW;
    int yy = y0 - 1 + r, xx = x0 - 1 + c;
    float4 l4 = make_float4(0.f, 0.f, 0.f, 0.f);
    float4 w4 = make_float4(0.f, 0.f, 0.f, 0.f);
    if (yy >= 0 && yy < H && xx >= 0 && xx < W) {
      float dv = dispb[yy * W + xx];
      float xsv = (float)xx - dv;
      float xc = fminf(fmaxf(xsv, 0.f), (float)(W - 1));
      float x0f = floorf(xc);
      float w = xc - x0f;
      int x0i = (int)x0f;
      int x1i = min(x0i + 1, W - 1);
      const float* l0 = lb + (size_t)yy * W;
      const float* r0 = rb + (size_t)yy * W;
      l4.x = l0[xx];
      l4.y = l0[(size_t)H * W + xx];
      l4.z = l0[2 * (size_t)H * W + xx];
      l4.w = dv;
      w4.x = r0[x0i] * (1.f - w) + r0[x1i] * w;
      w4.y = r0[(size_t)H * W + x0i] * (1.f - w) + r0[(size_t)H * W + x1i] * w;
      w4.z = r0[2 * (size_t)H * W + x0i] * (1.f - w) + r0[2 * (size_t)H * W + x1i] * w;
    }
    L4s[e] = l4; W4s[e] = w4;
  }
  __syncthreads();

  // ---- lg/rg emission (threads 0..255): 32x8 half-res pixels of this tile ----
  if (tid < 256) {
    int hx = tid & 31, hy = tid >> 5;
    int y2g = (y0 >> 1) + hy, x2g = (x0 >> 1) + hx;
    int i00 = (2 * hy + 1) * SW + (2 * hx + 1);
    float4 a00 = L4s[i00], a01 = L4s[i00 + 1], a10 = L4s[i00 + SW], a11 = L4s[i00 + SW + 1];
    float sl = 0.f;
    sl += a00.x + a01.x + a10.x + a11.x;
    sl += a00.y + a01.y + a10.y + a11.y;
    sl += a00.z + a01.z + a10.z + a11.z;
    float sr = 0.f;
    int yy2 = y0 + 2 * hy, xx2 = x0 + 2 * hx;
    #pragma unroll
    for (int c = 0; c < 3; c++) {
      const float* rp = rb + (size_t)(c * H + yy2) * W + xx2;
      sr += rp[0] + rp[1] + rp[W] + rp[W + 1];
    }
    size_t ho = (size_t)b * (H2 * W2) + (size_t)y2g * W2 + x2g;
    lg[ho] = sl * (1.f / 12.f);
    rg[ho] = sr * (1.f / 12.f);
  }

  float v[6];
  #pragma unroll
  for (int s = 0; s < 6; s++) v[s] = 0.f;

  {
    const int tx = tid & 63, ty = tid >> 6;
    const int x = x0 + tx, y = y0 + ty;
    const size_t gidx = (size_t)b * H * W + (size_t)y * W + x;
    const int ci = (ty + 1) * SW + (tx + 1);

    float sl[3] = {0,0,0}, sw[3] = {0,0,0}, sl2[3] = {0,0,0},
          sw2[3] = {0,0,0}, slw[3] = {0,0,0};
    float4 cl4, cw4, rl4, dl4;
    #pragma unroll
    for (int dy = -1; dy <= 1; dy++) {
      #pragma unroll
      for (int dx = -1; dx <= 1; dx++) {
        int ni = ci + dy * SW + dx;
        float4 a = L4s[ni];
        float4 wv = W4s[ni];
        sl[0] += a.x;  sl2[0] += a.x * a.x;  sw[0] += wv.x;  sw2[0] += wv.x * wv.x;  slw[0] += a.x * wv.x;
        sl[1] += a.y;  sl2[1] += a.y * a.y;  sw[1] += wv.y;  sw2[1] += wv.y * wv.y;  slw[1] += a.y * wv.y;
        sl[2] += a.z;  sl2[2] += a.z * a.z;  sw[2] += wv.z;  sw2[2] += wv.z * wv.z;  slw[2] += a.z * wv.z;
        if (dy == 0 && dx == 0) { cl4 = a; cw4 = wv; }
        if (dy == 0 && dx == 1) rl4 = a;
        if (dy == 1 && dx == 0) dl4 = a;
      }
    }
    float ds = cl4.w;

    // ---- gt anchor ----
    {
      float g = gt[gidx];
      float trust = (g > 2.0f) ? conf[gidx] * occ[gidx] : 0.f;
      v[0] = trust * fabsf(ds - g);
      v[1] = trust;
    }

    // ---- photometric ----
    {
      float xs = (float)x - ds;
      bool valid = (xs > 0.f) && (xs < (float)(W - 1));
      float cl[3] = {cl4.x, cl4.y, cl4.z};
      float cw[3] = {cw4.x, cw4.y, cw4.z};
      float ssm = 0.f, l1m = 0.f;
      #pragma unroll
      for (int c = 0; c < 3; c++) {
        float mx = sl[c] * (1.f / 9.f), my = sw[c] * (1.f / 9.f);
        float sx = fmaxf(sl2[c] * (1.f / 9.f) - mx * mx, 0.f);
        float sy = fmaxf(sw2[c] * (1.f / 9.f) - my * my, 0.f);
        float sxy = slw[c] * (1.f / 9.f) - mx * my;
        float n  = (2.f * mx * my + 1e-4f) * (2.f * sxy + 9e-4f);
        float dd = (mx * mx + my * my + 1e-4f) * (sx + sy + 9e-4f);
        float ss = (1.f - n / dd) * 0.5f;
        ss = fminf(fmaxf(ss, 0.f), 1.f);
        ssm += ss;
        l1m += fabsf(cl[c] - cw[c]);
      }
      ssm *= (1.f / 3.f); l1m *= (1.f / 3.f);
      float err = 0.85f * ssm + 0.15f * l1m;
      if (valid) { v[2] = err; v[3] = 1.f; }
    }

    // ---- smoothness ----
    if (x < W - 1) {
      float ddx = fabsf(rl4.w - ds);
      float idx = fabsf(rl4.x - cl4.x) + fabsf(rl4.y - cl4.y) + fabsf(rl4.z - cl4.z);
      v[4] = ddx * __expf(-idx * (1.f / 3.f));
    }
    if (y < H - 1) {
      float ddy = fabsf(dl4.w - ds);
      float idy = fabsf(dl4.x - cl4.x) + fabsf(dl4.y - cl4.y) + fabsf(dl4.z - cl4.z);
      v[5] = ddy * __expf(-idy * (1.f / 3.f));
    }
  }

  __shared__ float sm[16][6];
  int wave = threadIdx.x >> 6, lane = threadIdx.x & 63;
  #pragma unroll
  for (int s = 0; s < 6; s++) {
    float r = waveSum(v[s]);
    if (lane == 0) sm[wave][s] = r;
  }
  __syncthreads();
  if (threadIdx.x < 6) {
    float t = 0.f;
    #pragma unroll
    for (int q = 0; q < 16; q++) t += sm[q][threadIdx.x];
    atomicAdd(&acc[threadIdx.x], (double)t);   // relaxed; visible at k_ncc launch
  }
}

// -------- fused NCC disparity search, ALL 48 d's + inline sign/mag (R18) ----------
// R18 = R16's verified body + fence-free last-block composition:
//   * tid0 atomicAdds the block's 3 sums to acc[6..8] (f64, coherence-point op),
//   * a data-dependency barrier on the RETURN VALUES (asm consuming them,
//     "memory" clobber) guarantees completion before the relaxed ticket add,
//   * the last ticket holder reads acc via agent-scope atomic loads and
//     composes out[0]. No __threadfence -> no per-block L2 writeback
//     (R17 lesson: threadfence cost +60us across 1088 blocks).
// LDS layout identical to R16:
//   @0:    LGs 18x74=1332 (dead after LH) overlaid by RM 8x112 @0, RS @896
//   @1792: RGs 18x122 = 2196 | @3988: POOL 2304 | @6292: P1 8x25 | @6492: P2
__global__ __launch_bounds__(256) void k_ncc(const float* __restrict__ lg,
                                             const float* __restrict__ rg,
                                             const float* __restrict__ pred,
                                             double* __restrict__ acc,
                                             unsigned int* __restrict__ counter,
                                             float* __restrict__ out) {
  const int b = blockIdx.z;
  const int x0 = blockIdx.x * 64;
  const int y0 = blockIdx.y * 8;
  const int tid = threadIdx.x;

  __shared__ __align__(16) float SM[6692];
  float* LGs = SM;             // 18 x 74
  float* RM  = SM;             // 8 x 112 (overlays dead LGs)
  float* RS  = SM + 896;       // 8 x 112
  float* RGs = SM + 1792;      // 18 x 122
  float* POOL = SM + 3988;     // 2304
  float* P1 = SM + 6292;       // 8 x 25
  float* P2 = SM + 6492;

  const float* lgb = lg + (size_t)b * (H2 * W2);
  const float* rgb = rg + (size_t)b * (H2 * W2);

  for (int e = tid; e < 18 * 74; e += 256) {
    int r = e / 74, c = e % 74;
    int gy = y0 - 5 + r, gxx = x0 - 5 + c;
    LGs[e] = (gy >= 0 && gy < H2 && gxx >= 0 && gxx < W2) ? lgb[gy * W2 + gxx] : 0.f;
  }
  const int col0RG = x0 - 29;       // x0 - 5 + dmin, dmin = -24
  for (int e = tid; e < 18 * 122; e += 256) {
    int r = e / 122, c = e % 122;
    int gy = y0 - 5 + r, gxx = col0RG + c;
    RGs[e] = (gy >= 0 && gy < H2 && gxx >= 0 && gxx < W2) ? rgb[gy * W2 + gxx] : 0.f;
  }
  __syncthreads();

  // ---- LH pass (horizontal 11-sums of lg, lg^2) + lgc register cache ----
  const int hg = tid & 7, hr = tid >> 3;
  float lgc[18];
  float* LH1 = POOL;           // 18 x 64
  float* LH2 = POOL + 1152;
  if (hr < 18) {
    #pragma unroll
    for (int k = 0; k < 18; k++) lgc[k] = LGs[hr * 74 + 8 * hg + k];
    float w1[8], w2[8];
    float s1 = 0.f, s2 = 0.f;
    #pragma unroll
    for (int k = 0; k < 11; k++) { s1 += lgc[k]; s2 += lgc[k] * lgc[k]; }
    w1[0] = s1; w2[0] = s2;
    #pragma unroll
    for (int j = 1; j < 8; j++) {
      s1 += lgc[j + 10] - lgc[j - 1];
      s2 += lgc[j + 10] * lgc[j + 10] - lgc[j - 1] * lgc[j - 1];
      w1[j] = s1; w2[j] = s2;
    }
    *(float4*)&LH1[hr * 64 + 8 * hg]     = make_float4(w1[0], w1[1], w1[2], w1[3]);
    *(float4*)&LH1[hr * 64 + 8 * hg + 4] = make_float4(w1[4], w1[5], w1[6], w1[7]);
    *(float4*)&LH2[hr * 64 + 8 * hg]     = make_float4(w2[0], w2[1], w2[2], w2[3]);
    *(float4*)&LH2[hr * 64 + 8 * hg + 4] = make_float4(w2[4], w2[5], w2[6], w2[7]);
  }
  // ---- border column sums (head: global cols 0..23; tail: 456..479) ----
  const bool headT = (x0 == 0);
  const bool tailT = (x0 == 448);
  if (headT || tailT) {
    int gcol0 = headT ? 0 : 456;
    for (int e = tid; e < 8 * 24; e += 256) {
      int y = e / 24, i = e % 24;
      int lc = gcol0 + i - col0RG;
      float v1 = 0.f, v2 = 0.f;
      if (lc >= 0 && lc < 122) {
        #pragma unroll
        for (int dy = 0; dy < 11; dy++) {
          float v = RGs[(y + dy) * 122 + lc];
          v1 += v; v2 += v * v;
        }
      }
      P1[y * 25 + i + 1] = v1;
      P2[y * 25 + i + 1] = v2;
    }
  }
  __syncthreads();

  if ((headT || tailT) && tid < 8) {
    int y = tid;
    float s1 = 0.f, s2 = 0.f;
    P1[y * 25] = 0.f; P2[y * 25] = 0.f;
    for (int k = 0; k < 24; k++) {
      s1 += P1[y * 25 + k + 1]; P1[y * 25 + k + 1] = s1;
      s2 += P2[y * 25 + k + 1]; P2[y * 25 + k + 1] = s2;
    }
  }
  const int vx = tid & 63;
  const int vys = (tid >> 6) * 2;    // 4 waves x 2 rows = 8 output rows
  float lmS[2], lsS[2];   // 121-scaled left mean / std
  {
    float s1 = 0.f, s2 = 0.f;
    #pragma unroll
    for (int dy = 0; dy < 11; dy++) { s1 += LH1[(vys + dy) * 64 + vx]; s2 += LH2[(vys + dy) * 64 + vx]; }
    #pragma unroll
    for (int k = 0; k < 2; k++) {
      if (k) {
        s1 += LH1[(vys + k + 10) * 64 + vx] - LH1[(vys + k - 1) * 64 + vx];
        s2 += LH2[(vys + k + 10) * 64 + vx] - LH2[(vys + k - 1) * 64 + vx];
      }
      float m = s1 * (1.f / 121.f);
      float s = sqrtf(fmaxf(s2 * (1.f / 121.f) - m * m, 1e-8f));
      lmS[k] = m * 121.f;
      lsS[k] = s * 121.f;
    }
  }
  __syncthreads();

  // ---- VR pass: vertical 11-sums of rg, rg^2 (POOL, overwrites LH) ----
  float* VR1 = POOL;           // 8 x 122
  float* VR2 = POOL + 976;
  if (tid < 244) {
    int c = tid % 122;
    int rr0 = (tid / 122) * 4;
    float s1 = 0.f, s2 = 0.f;
    #pragma unroll
    for (int dy = 0; dy < 11; dy++) {
      float v = RGs[(rr0 + dy) * 122 + c];
      s1 += v; s2 += v * v;
    }
    VR1[rr0 * 122 + c] = s1; VR2[rr0 * 122 + c] = s2;
    #pragma unroll
    for (int k = 1; k < 4; k++) {
      float vin  = RGs[(rr0 + k + 10) * 122 + c];
      float vout = RGs[(rr0 + k - 1) * 122 + c];
      s1 += vin - vout;
      s2 += vin * vin - vout * vout;
      VR1[(rr0 + k) * 122 + c] = s1; VR2[(rr0 + k) * 122 + c] = s2;
    }
  }
  __syncthreads();

  // ---- RV pass fused with moment transform -> planar RM (mean), RS (std) ----
  {
    int r = tid >> 5, seg = tid & 31;
    int c0 = seg * 4;
    if (c0 < 112) {
      float s1 = 0.f, s2 = 0.f;
      #pragma unroll
      for (int m = 0; m < 11; m++) { s1 += VR1[r * 122 + c0 + m]; s2 += VR2[r * 122 + c0 + m]; }
      #pragma unroll
      for (int j = 0; j < 4; j++) {
        if (j) {
          s1 += VR1[r * 122 + c0 + j + 10] - VR1[r * 122 + c0 + j - 1];
          s2 += VR2[r * 122 + c0 + j + 10] - VR2[r * 122 + c0 + j - 1];
        }
        float rm = s1 * (1.f / 121.f);
        float rstd = sqrtf(fmaxf(s2 * (1.f / 121.f) - rm * rm, 1e-8f));
        RM[r * 112 + c0 + j] = rm;
        RS[r * 112 + c0 + j] = rstd;
      }
    }
  }
  __syncthreads();

  // ---- d loop: 24 pairs covering d in [-24..-1] u [1..24], ascending ----
  float* CH0 = POOL;           // 18 x 64
  float* CH1 = POOL + 1152;
  const int gx = x0 + vx;
  float bnum[2], bden[2], bdd[2];
  #pragma unroll
  for (int k = 0; k < 2; k++) { bnum[k] = -1.f; bden[k] = 1.f; bdd[k] = 0.f; }

  for (int it = 0; it < 24; ++it) {
    const int d0 = (it < 12) ? (2 * it - 24) : (2 * it - 23);
    if (hr < 18) {
      const int c0 = 8 * hg + d0 + 24;
      float rgv[19];
      #pragma unroll
      for (int j = 0; j < 19; j++) rgv[j] = RGs[hr * 122 + c0 + j];
      float ca[8], cb[8];
      float sa = 0.f, sb = 0.f;
      #pragma unroll
      for (int k = 0; k < 11; k++) { sa += lgc[k] * rgv[k]; sb += lgc[k] * rgv[k + 1]; }
      ca[0] = sa; cb[0] = sb;
      #pragma unroll
      for (int j = 1; j < 8; j++) {
        sa += lgc[j + 10] * rgv[j + 10] - lgc[j - 1] * rgv[j - 1];
        sb += lgc[j + 10] * rgv[j + 11] - lgc[j - 1] * rgv[j];
        ca[j] = sa; cb[j] = sb;
      }
      *(float4*)&CH0[hr * 64 + 8 * hg]     = make_float4(ca[0], ca[1], ca[2], ca[3]);
      *(float4*)&CH0[hr * 64 + 8 * hg + 4] = make_float4(ca[4], ca[5], ca[6], ca[7]);
      *(float4*)&CH1[hr * 64 + 8 * hg]     = make_float4(cb[0], cb[1], cb[2], cb[3]);
      *(float4*)&CH1[hr * 64 + 8 * hg + 4] = make_float4(cb[4], cb[5], cb[6], cb[7]);
    }
    __syncthreads();
    {
      float a0 = 0.f, a1 = 0.f;
      #pragma unroll
      for (int dy = 0; dy < 11; dy++) { a0 += CH0[(vys + dy) * 64 + vx]; a1 += CH1[(vys + dy) * 64 + vx]; }
      #pragma unroll
      for (int k = 0; k < 2; k++) {
        if (k) {
          a0 += CH0[(vys + k + 10) * 64 + vx] - CH0[(vys + k - 1) * 64 + vx];
          a1 += CH1[(vys + k + 10) * 64 + vx] - CH1[(vys + k - 1) * 64 + vx];
        }
        #pragma unroll
        for (int h = 0; h < 2; h++) {
          int d = d0 + h;
          float cs = h ? a1 : a0;            // raw 121-sum of lg*rg_shift
          int rvi = vx + d + 24;
          float rm   = RM[(vys + k) * 112 + rvi];
          float rstd = RS[(vys + k) * 112 + rvi];
          bool eh = (d > 0) ? (gx < 5) : (gx > 474);   // implies x0==0 / x0==448
          if (eh) {
            float rs = rm * 121.f;
            float r2 = (rstd * rstd + rm * rm) * 121.f;
            int a, bI;
            if (d > 0) { a = max(gx - 5 + d, 0); bI = d; }
            else       { a = 24 + d; bI = min(gx + 5 + d, 479) - 455; }
            rs -= P1[(vys + k) * 25 + bI] - P1[(vys + k) * 25 + a];
            r2 -= P2[(vys + k) * 25 + bI] - P2[(vys + k) * 25 + a];
            rm = rs * (1.f / 121.f);
            rstd = sqrtf(fmaxf(r2 * (1.f / 121.f) - rm * rm, 1e-8f));
          }
          float num = __builtin_fmaf(-lmS[k], rm, cs);
          float den = __builtin_fmaf(lsS[k], rstd, 1.21e-6f);
          if (num * bden[k] > bnum[k] * den) { bnum[k] = num; bden[k] = den; bdd[k] = (float)d; }
        }
      }
    }
    __syncthreads();
  }

  // ---- inline sign/magnitude epilogue ----
  float v6 = 0.f, v7 = 0.f, v8 = 0.f;
  if (gx < W2) {
    const float* pb = pred + (size_t)b * H * W;
    #pragma unroll
    for (int k = 0; k < 2; k++) {
      float bc = bnum[k] / bden[k];
      if (bc > 0.3f) {
        float nd = bdd[k] * 2.f;
        float sgn = (nd > 0.f) ? 1.f : ((nd < 0.f) ? -1.f : 0.f);
        const float* p0 = pb + (size_t)(2 * (y0 + vys + k)) * W + 2 * gx;
        float p00 = p0[0], p01 = p0[1];
        float p10 = p0[W], p11 = p0[W + 1];
        v6 += fmaxf(-p00 * sgn, 0.f) + fmaxf(-p01 * sgn, 0.f)
            + fmaxf(-p10 * sgn, 0.f) + fmaxf(-p11 * sgn, 0.f);
        v7 += bc * (fabsf(p00 - nd) + fabsf(p01 - nd)
                  + fabsf(p10 - nd) + fabsf(p11 - nd));
        v8 += 4.f;
      }
    }
  }
  // block reduce into P1 region (P tables dead after d-loop)
  float* red = P1;   // 4 waves x 3 sums
  int wave = tid >> 6, lane = tid & 63;
  float r;
  r = waveSum(v6); if (lane == 0) red[wave * 3 + 0] = r;
  r = waveSum(v7); if (lane == 0) red[wave * 3 + 1] = r;
  r = waveSum(v8); if (lane == 0) red[wave * 3 + 2] = r;
  __syncthreads();

  if (tid == 0) {
    float t6 = red[0] + red[3] + red[6] + red[9];
    float t7 = red[1] + red[4] + red[7] + red[10];
    float t8 = red[2] + red[5] + red[8] + red[11];
    // coherence-point adds; returns force completion before the ticket below
    double o6 = atomicAdd(&acc[6], (double)t6);
    double o7 = atomicAdd(&acc[7], (double)t7);
    double o8 = atomicAdd(&acc[8], (double)t8);
    // data-dependency + compiler barrier: ticket may not issue until the three
    // adds have executed at the coherence point (their old values returned)
    asm volatile("" :: "v"(o6), "v"(o7), "v"(o8) : "memory");
    unsigned int old = atomicAdd(counter, 1u);
    if (old == (unsigned int)(NBLK3 - 1)) {
      // all 1088 tickets in => every block's acc adds completed (each ticket
      // was dependency-ordered after its own adds). Read via agent-scope
      // atomic loads (coherent with the f64 atomics), compose in double.
      double a[9];
      #pragma unroll
      for (int s = 0; s < 9; s++)
        a[s] = __hip_atomic_load(&acc[s], __ATOMIC_RELAXED, __HIP_MEMORY_SCOPE_AGENT);
      double gtl = a[0] / fmax(a[1], 1.0);
      double ph  = a[2] / fmax(a[3], 1.0);
      double n   = fmax(a[8], 1.0);
      double smv = 0.3 * (a[6] / n) + 0.7 * (a[7] / n);
      double smo = a[4] * (1.0 / ((double)B * H * (W - 1)))
                 + a[5] * (1.0 / ((double)B * (H - 1) * W));
      out[0] = (float)(gtl + ph + 0.5 * smv + 0.1 * smo);
    }
  }
}

extern "C" void kernel_launch(void* const* d_in, const int* in_sizes, int n_in,
                              void* d_out, int out_size, void* d_ws, size_t ws_size,
                              hipStream_t stream) {
  const float* pred  = (const float*)d_in[0];
  const float* gt    = (const float*)d_in[1];
  const float* conf  = (const float*)d_in[2];
  const float* occ   = (const float*)d_in[3];
  const float* left  = (const float*)d_in[4];
  const float* right = (const float*)d_in[5];
  float* out = (float*)d_out;

  // ws layout: acc[9] doubles @0, counter @96B, lg @128B, rg after
  double* acc = (double*)d_ws;
  unsigned int* counter = (unsigned int*)((char*)d_ws + 96);
  float* lg = (float*)((char*)d_ws + 128);
  float* rg = lg + (size_t)NH;

  hipMemsetAsync(d_ws, 0, 128, stream);   // zero acc + counter (graph-legal)

  k_pix<<<NBLK, 1024, 0, stream>>>(pred, gt, conf, occ, left, right,
                                   lg, rg, acc);

  dim3 nccGrid(8, 34, B);   // x-tiles, y-tiles (272/8), batch (all d's per block)
  k_ncc<<<nccGrid, 256, 0, stream>>>(lg, rg, pred, acc, counter, out);
}